// Round 5
// baseline (253.289 us; speedup 1.0000x reference)
//
#include <hip/hip_runtime.h>
#include <hip/hip_bf16.h>

#define B_ROWS 8192
#define D_DIM  2048
#define C_DIM  1000
#define C_PAD  1024

#define EPS32   1.1920928955078125e-07f
// GAMMA = 1/exp(100) ~ 3.7e-44. GAMMA*rex ~ 1e-40 << ulp(h3~6.9) ~ 4.8e-7,
// so loss == mean(h3) exactly in fp32. rex pipeline deleted.

typedef __attribute__((ext_vector_type(8))) short short8;   // 8 bf16 = 4 VGPRs
typedef __attribute__((ext_vector_type(4))) float f32x4;    // MFMA accumulator

#define GLOAD_LDS16(gptr, lptr) \
  __builtin_amdgcn_global_load_lds((const __attribute__((address_space(1))) void*)(gptr), \
                                   (__attribute__((address_space(3))) void*)(lptr), 16, 0, 0)

__device__ inline unsigned short f2bf(float x) {
  union { __hip_bfloat16 b; unsigned short u; } cv;
  cv.b = __float2bfloat16(x);
  return cv.u;
}

__device__ inline float wave_red(float v) {
#pragma unroll
  for (int off = 32; off > 0; off >>= 1) v += __shfl_down(v, off, 64);
  return v;
}

// ---- P: cast cls_w [1000,2048] f32 -> bf16 padded to [1024,2048] (pad rows = 0)
__global__ __launch_bounds__(256) void prep(const float* __restrict__ cls_w,
                                            __hip_bfloat16* __restrict__ clsw_bf) {
  int j = (blockIdx.x * 256 + threadIdx.x) * 8;   // element idx in padded [1024][2048]
  int row = j >> 11;
  int col = j & 2047;
  union { unsigned short u[8]; uint4 v; } pk;
  if (row < C_DIM) {
    const float* src = cls_w + (size_t)row * D_DIM + col;
#pragma unroll
    for (int i = 0; i < 8; ++i) pk.u[i] = f2bf(src[i]);
  } else {
#pragma unroll
    for (int i = 0; i < 8; ++i) pk.u[i] = 0;
  }
  *(uint4*)((unsigned short*)clsw_bf + j) = pk.v;
}

// ---- B: pure streaming z_bf = bf16(feature + eps). 160 MB total traffic.
__global__ __launch_bounds__(256) void fuse_z(const float4* __restrict__ f4,
                                              const float4* __restrict__ e4,
                                              uint2* __restrict__ z) {
  int tid = blockIdx.x * 256 + threadIdx.x;
  const int stride = 2048 * 256;
#pragma unroll
  for (int k = 0; k < 8; ++k) {
    int i = tid + k * stride;
    float4 f = f4[i];
    float4 e = e4[i];
    union { unsigned short u[4]; uint2 v; } pz;
    pz.u[0] = f2bf(f.x + e.x);
    pz.u[1] = f2bf(f.y + e.y);
    pz.u[2] = f2bf(f.z + e.z);
    pz.u[3] = f2bf(f.w + e.w);
    z[i] = pz.v;
  }
}

// ---- C: probs_raw = z @ cls_w^T + cls_b
// 128x128 tile, BK=64, 4 waves x (4x4) 16x16x32 MFMA.
// LDS layout XOR-swizzled: 16B chunk (row, cc) lives at slot row*8 + (cc ^ (row&7)).
__global__ __launch_bounds__(256) void gemm_bt(const __hip_bfloat16* __restrict__ A,
                                               const __hip_bfloat16* __restrict__ Bt,
                                               const float* __restrict__ cls_b,
                                               float* __restrict__ out) {
  __shared__ __align__(16) __hip_bfloat16 sA[128 * 64];
  __shared__ __align__(16) __hip_bfloat16 sB[128 * 64];
  const int tid = threadIdx.x;
  const int m0 = blockIdx.x * 128;
  const int n0 = blockIdx.y * 128;
  const int w = tid >> 6, lane = tid & 63;
  const int wm = (w & 1) * 64, wn = (w >> 1) * 64;
  const int l15 = lane & 15, quad = lane >> 4;

  f32x4 acc[4][4] = {};

  for (int k0 = 0; k0 < D_DIM; k0 += 64) {
#pragma unroll
    for (int i = 0; i < 4; ++i) {
      int j = i * 256 + tid;          // LDS slot: 1024 chunks of 16B per 128x64 tile
      int row = j >> 3;
      int cc = (j & 7) ^ (row & 7);   // inverse of the swizzle (XOR is an involution)
      const __hip_bfloat16* srcA = A + (size_t)(m0 + row) * D_DIM + k0 + cc * 8;
      const __hip_bfloat16* srcB = Bt + (size_t)(n0 + row) * D_DIM + k0 + cc * 8;
      GLOAD_LDS16(srcA, &sA[j * 8]);
      GLOAD_LDS16(srcB, &sB[j * 8]);
    }
    __syncthreads();
#pragma unroll
    for (int kk = 0; kk < 64; kk += 32) {
      const int ccr = (kk >> 3) + quad;   // which 8-elem chunk along K
      short8 af[4], bfr[4];
#pragma unroll
      for (int i = 0; i < 4; ++i) {
        int r = wm + i * 16 + l15;
        af[i] = *(const short8*)&sA[(r * 8 + (ccr ^ (r & 7))) * 8];
      }
#pragma unroll
      for (int jn = 0; jn < 4; ++jn) {
        int r = wn + jn * 16 + l15;
        bfr[jn] = *(const short8*)&sB[(r * 8 + (ccr ^ (r & 7))) * 8];
      }
#pragma unroll
      for (int i = 0; i < 4; ++i)
#pragma unroll
        for (int jn = 0; jn < 4; ++jn)
          acc[i][jn] = __builtin_amdgcn_mfma_f32_16x16x32_bf16(af[i], bfr[jn], acc[i][jn], 0, 0, 0);
    }
    __syncthreads();
  }

  // epilogue: C/D layout col=lane&15, row=quad*4+reg  (m89-verified)
#pragma unroll
  for (int i = 0; i < 4; ++i) {
    int row = m0 + wm + i * 16 + quad * 4;
#pragma unroll
    for (int jn = 0; jn < 4; ++jn) {
      int col = n0 + wn + jn * 16 + l15;
      if (col < C_DIM) {
        float bias = cls_b[col];
#pragma unroll
        for (int r = 0; r < 4; ++r)
          out[(size_t)(row + r) * C_DIM + col] = acc[i][jn][r] + bias;
      }
    }
  }
}

// ---- D: wave-autonomous per-row normalize+clamp+log. One wave per row; lane
// owns 16 cols as 4 float4 chunks. rowloss[b] = h3 (GAMMA term is sub-ulp).
__global__ __launch_bounds__(256) void rownorm(float* __restrict__ out,
                                               const int* __restrict__ target,
                                               float* __restrict__ rowloss) {
  int b = blockIdx.x * 4 + (threadIdx.x >> 6);
  int lane = threadIdx.x & 63;
  float* row = out + (size_t)b * C_DIM;

  float v[16];
  float s = 0.f;
#pragma unroll
  for (int k = 0; k < 4; ++k) {
    int c = k * 256 + lane * 4;
    if (c + 3 < C_DIM) {
      float4 f = *(const float4*)(row + c);
      v[k * 4 + 0] = f.x; v[k * 4 + 1] = f.y; v[k * 4 + 2] = f.z; v[k * 4 + 3] = f.w;
    } else {
#pragma unroll
      for (int i = 0; i < 4; ++i) v[k * 4 + i] = (c + i < C_DIM) ? row[c + i] : 0.f;
    }
    s += v[k * 4 + 0] + v[k * 4 + 1] + v[k * 4 + 2] + v[k * 4 + 3];
  }
  s = wave_red(s);
  float inv = 1.0f / __shfl(s, 0, 64);
  int t = target[b];

#pragma unroll
  for (int k = 0; k < 4; ++k) {
    int c = k * 256 + lane * 4;
    float lg[4];
#pragma unroll
    for (int i = 0; i < 4; ++i) {
      float p = v[k * 4 + i] * inv;
      p = fminf(fmaxf(p, EPS32), 1.0f - EPS32);
      lg[i] = __logf(p);
      if (c + i == t) rowloss[b] = -lg[i];
    }
    if (c + 3 < C_DIM) {
      *(float4*)(row + c) = make_float4(lg[0], lg[1], lg[2], lg[3]);
    } else {
#pragma unroll
      for (int i = 0; i < 4; ++i) if (c + i < C_DIM) row[c + i] = lg[i];
    }
  }
}

// ---- E: loss = mean(rowloss)
__global__ __launch_bounds__(256) void finalize(const float* __restrict__ rowloss,
                                                float* __restrict__ out_loss) {
  int tid = threadIdx.x;
  float s = 0.f;
  for (int i = tid; i < B_ROWS; i += 256) s += rowloss[i];
  s = wave_red(s);
  __shared__ float sm[4];
  if ((tid & 63) == 0) sm[tid >> 6] = s;
  __syncthreads();
  if (tid == 0) out_loss[0] = (sm[0] + sm[1] + sm[2] + sm[3]) * (1.0f / B_ROWS);
}

extern "C" void kernel_launch(void* const* d_in, const int* in_sizes, int n_in,
                              void* d_out, int out_size, void* d_ws, size_t ws_size,
                              hipStream_t stream) {
  const float* feature = (const float*)d_in[0];
  const float* cls_w   = (const float*)d_in[3];
  const float* cls_b   = (const float*)d_in[4];
  const float* eps     = (const float*)d_in[5];
  const int*   target  = (const int*)d_in[6];
  float* out = (float*)d_out;
  float* out_loss = out + (size_t)B_ROWS * C_DIM;

  char* ws = (char*)d_ws;
  __hip_bfloat16* z_bf    = (__hip_bfloat16*)ws;                // 33554432 B
  __hip_bfloat16* clsw_bf = (__hip_bfloat16*)(ws + 33554432);   //  4194304 B
  float*          rowloss = (float*)(ws + 33554432 + 4194304);  //    32768 B

  prep<<<dim3(1024), 256, 0, stream>>>(cls_w, clsw_bf);
  fuse_z<<<dim3(2048), 256, 0, stream>>>((const float4*)feature, (const float4*)eps, (uint2*)z_bf);
  gemm_bt<<<dim3(B_ROWS / 128, C_PAD / 128), 256, 0, stream>>>(z_bf, clsw_bf, cls_b, out);
  rownorm<<<dim3(B_ROWS / 4), 256, 0, stream>>>(out, target, rowloss);
  finalize<<<dim3(1), 256, 0, stream>>>(rowloss, out_loss);
}

// Round 6
// 237.289 us; speedup vs baseline: 1.0674x; 1.0674x over previous
//
#include <hip/hip_runtime.h>
#include <hip/hip_bf16.h>

#define B_ROWS 8192
#define D_DIM  2048
#define C_DIM  1000
#define C_PAD  1024

#define EPS32   1.1920928955078125e-07f
// GAMMA = 1/exp(100) ~ 3.7e-44. GAMMA*rex ~ 1e-40 << ulp(h3~6.9) ~ 4.8e-7,
// so loss == mean(h3) exactly in fp32. rex pipeline deleted (round 5).

typedef __attribute__((ext_vector_type(8))) short short8;   // 8 bf16 = 4 VGPRs
typedef __attribute__((ext_vector_type(4))) float f32x4;    // MFMA accumulator

#define GLOAD_LDS16(gptr, lptr) \
  __builtin_amdgcn_global_load_lds((const __attribute__((address_space(1))) void*)(gptr), \
                                   (__attribute__((address_space(3))) void*)(lptr), 16, 0, 0)

__device__ inline unsigned short f2bf(float x) {
  union { __hip_bfloat16 b; unsigned short u; } cv;
  cv.b = __float2bfloat16(x);
  return cv.u;
}

__device__ inline float wave_red(float v) {
#pragma unroll
  for (int off = 32; off > 0; off >>= 1) v += __shfl_down(v, off, 64);
  return v;
}

// ---- B+P merged:
//   blocks [0,16384):      z_bf[i] = bf16(feature[i] + eps[i]), one float4-pair
//                          per thread (max TLP: ~32 waves/CU, 2 loads each).
//   blocks [16384,17408):  cast cls_w [1000,2048] -> bf16 padded [1024,2048].
__global__ __launch_bounds__(256) void fuse_z(const float4* __restrict__ f4,
                                              const float4* __restrict__ e4,
                                              uint2* __restrict__ z,
                                              const float* __restrict__ cls_w,
                                              __hip_bfloat16* __restrict__ clsw_bf) {
  int bid = blockIdx.x;
  if (bid < 16384) {
    int i = bid * 256 + threadIdx.x;
    float4 f = f4[i];
    float4 e = e4[i];
    union { unsigned short u[4]; uint2 v; } pz;
    pz.u[0] = f2bf(f.x + e.x);
    pz.u[1] = f2bf(f.y + e.y);
    pz.u[2] = f2bf(f.z + e.z);
    pz.u[3] = f2bf(f.w + e.w);
    z[i] = pz.v;
  } else {
    int j = ((bid - 16384) * 256 + threadIdx.x) * 8;   // elem idx in [1024][2048]
    int row = j >> 11;
    int col = j & 2047;
    union { unsigned short u[8]; uint4 v; } pk;
    if (row < C_DIM) {
      const float* src = cls_w + (size_t)row * D_DIM + col;
#pragma unroll
      for (int i2 = 0; i2 < 8; ++i2) pk.u[i2] = f2bf(src[i2]);
    } else {
#pragma unroll
      for (int i2 = 0; i2 < 8; ++i2) pk.u[i2] = 0;
    }
    *(uint4*)((unsigned short*)clsw_bf + j) = pk.v;
  }
}

// ---- C: probs_raw = z @ cls_w^T + cls_b
// 128x128 tile, BK=64, 4 waves x (4x4) 16x16x32 MFMA.
// LDS layout XOR-swizzled: 16B chunk (row, cc) lives at slot row*8 + (cc ^ (row&7)).
__global__ __launch_bounds__(256) void gemm_bt(const __hip_bfloat16* __restrict__ A,
                                               const __hip_bfloat16* __restrict__ Bt,
                                               const float* __restrict__ cls_b,
                                               float* __restrict__ out) {
  __shared__ __align__(16) __hip_bfloat16 sA[128 * 64];
  __shared__ __align__(16) __hip_bfloat16 sB[128 * 64];
  const int tid = threadIdx.x;
  const int m0 = blockIdx.x * 128;
  const int n0 = blockIdx.y * 128;
  const int w = tid >> 6, lane = tid & 63;
  const int wm = (w & 1) * 64, wn = (w >> 1) * 64;
  const int l15 = lane & 15, quad = lane >> 4;

  f32x4 acc[4][4] = {};

  for (int k0 = 0; k0 < D_DIM; k0 += 64) {
#pragma unroll
    for (int i = 0; i < 4; ++i) {
      int j = i * 256 + tid;          // LDS slot: 1024 chunks of 16B per 128x64 tile
      int row = j >> 3;
      int cc = (j & 7) ^ (row & 7);   // inverse of the swizzle (XOR is an involution)
      const __hip_bfloat16* srcA = A + (size_t)(m0 + row) * D_DIM + k0 + cc * 8;
      const __hip_bfloat16* srcB = Bt + (size_t)(n0 + row) * D_DIM + k0 + cc * 8;
      GLOAD_LDS16(srcA, &sA[j * 8]);
      GLOAD_LDS16(srcB, &sB[j * 8]);
    }
    __syncthreads();
#pragma unroll
    for (int kk = 0; kk < 64; kk += 32) {
      const int ccr = (kk >> 3) + quad;   // which 8-elem chunk along K
      short8 af[4], bfr[4];
#pragma unroll
      for (int i = 0; i < 4; ++i) {
        int r = wm + i * 16 + l15;
        af[i] = *(const short8*)&sA[(r * 8 + (ccr ^ (r & 7))) * 8];
      }
#pragma unroll
      for (int jn = 0; jn < 4; ++jn) {
        int r = wn + jn * 16 + l15;
        bfr[jn] = *(const short8*)&sB[(r * 8 + (ccr ^ (r & 7))) * 8];
      }
#pragma unroll
      for (int i = 0; i < 4; ++i)
#pragma unroll
        for (int jn = 0; jn < 4; ++jn)
          acc[i][jn] = __builtin_amdgcn_mfma_f32_16x16x32_bf16(af[i], bfr[jn], acc[i][jn], 0, 0, 0);
    }
    __syncthreads();
  }

  // epilogue: C/D layout col=lane&15, row=quad*4+reg  (m89-verified)
#pragma unroll
  for (int i = 0; i < 4; ++i) {
    int row = m0 + wm + i * 16 + quad * 4;
#pragma unroll
    for (int jn = 0; jn < 4; ++jn) {
      int col = n0 + wn + jn * 16 + l15;
      if (col < C_DIM) {
        float bias = cls_b[col];
#pragma unroll
        for (int r = 0; r < 4; ++r)
          out[(size_t)(row + r) * C_DIM + col] = acc[i][jn][r] + bias;
      }
    }
  }
}

// ---- D: wave-autonomous per-row normalize+clamp+log. One wave per row; lane
// owns 16 cols as 4 float4 chunks. rowloss[b] = h3 (GAMMA term is sub-ulp).
__global__ __launch_bounds__(256) void rownorm(float* __restrict__ out,
                                               const int* __restrict__ target,
                                               float* __restrict__ rowloss) {
  int b = blockIdx.x * 4 + (threadIdx.x >> 6);
  int lane = threadIdx.x & 63;
  float* row = out + (size_t)b * C_DIM;

  float v[16];
  float s = 0.f;
#pragma unroll
  for (int k = 0; k < 4; ++k) {
    int c = k * 256 + lane * 4;
    if (c + 3 < C_DIM) {
      float4 f = *(const float4*)(row + c);
      v[k * 4 + 0] = f.x; v[k * 4 + 1] = f.y; v[k * 4 + 2] = f.z; v[k * 4 + 3] = f.w;
    } else {
#pragma unroll
      for (int i = 0; i < 4; ++i) v[k * 4 + i] = (c + i < C_DIM) ? row[c + i] : 0.f;
    }
    s += v[k * 4 + 0] + v[k * 4 + 1] + v[k * 4 + 2] + v[k * 4 + 3];
  }
  s = wave_red(s);
  float inv = 1.0f / __shfl(s, 0, 64);
  int t = target[b];

#pragma unroll
  for (int k = 0; k < 4; ++k) {
    int c = k * 256 + lane * 4;
    float lg[4];
#pragma unroll
    for (int i = 0; i < 4; ++i) {
      float p = v[k * 4 + i] * inv;
      p = fminf(fmaxf(p, EPS32), 1.0f - EPS32);
      lg[i] = __logf(p);
      if (c + i == t) rowloss[b] = -lg[i];
    }
    if (c + 3 < C_DIM) {
      *(float4*)(row + c) = make_float4(lg[0], lg[1], lg[2], lg[3]);
    } else {
#pragma unroll
      for (int i = 0; i < 4; ++i) if (c + i < C_DIM) row[c + i] = lg[i];
    }
  }
}

// ---- E: loss = mean(rowloss)
__global__ __launch_bounds__(256) void finalize(const float* __restrict__ rowloss,
                                                float* __restrict__ out_loss) {
  int tid = threadIdx.x;
  float s = 0.f;
  for (int i = tid; i < B_ROWS; i += 256) s += rowloss[i];
  s = wave_red(s);
  __shared__ float sm[4];
  if ((tid & 63) == 0) sm[tid >> 6] = s;
  __syncthreads();
  if (tid == 0) out_loss[0] = (sm[0] + sm[1] + sm[2] + sm[3]) * (1.0f / B_ROWS);
}

extern "C" void kernel_launch(void* const* d_in, const int* in_sizes, int n_in,
                              void* d_out, int out_size, void* d_ws, size_t ws_size,
                              hipStream_t stream) {
  const float* feature = (const float*)d_in[0];
  const float* cls_w   = (const float*)d_in[3];
  const float* cls_b   = (const float*)d_in[4];
  const float* eps     = (const float*)d_in[5];
  const int*   target  = (const int*)d_in[6];
  float* out = (float*)d_out;
  float* out_loss = out + (size_t)B_ROWS * C_DIM;

  char* ws = (char*)d_ws;
  __hip_bfloat16* z_bf    = (__hip_bfloat16*)ws;                // 33554432 B
  __hip_bfloat16* clsw_bf = (__hip_bfloat16*)(ws + 33554432);   //  4194304 B
  float*          rowloss = (float*)(ws + 33554432 + 4194304);  //    32768 B

  fuse_z<<<dim3(16384 + 1024), 256, 0, stream>>>((const float4*)feature, (const float4*)eps,
                                                 (uint2*)z_bf, cls_w, clsw_bf);
  gemm_bt<<<dim3(B_ROWS / 128, C_PAD / 128), 256, 0, stream>>>(z_bf, clsw_bf, cls_b, out);
  rownorm<<<dim3(B_ROWS / 4), 256, 0, stream>>>(out, target, rowloss);
  finalize<<<dim3(1), 256, 0, stream>>>(rowloss, out_loss);
}